// Round 1
// baseline (913.174 us; speedup 1.0000x reference)
//
#include <hip/hip_runtime.h>
#include <hip/hip_bf16.h>
#include <cstdint>
#include <cmath>

typedef __attribute__((ext_vector_type(4))) float f32x4;
typedef __attribute__((ext_vector_type(8))) short bf16x8;

// ---------------------------------------------------------------------------
// global -> LDS async copy, 16B per lane. LDS dest = wave-uniform base + lane*16.
// ---------------------------------------------------------------------------
__device__ __forceinline__ void gload_lds16(const void* g, void* l) {
    __builtin_amdgcn_global_load_lds(
        (const __attribute__((address_space(1))) void*)g,
        (__attribute__((address_space(3))) void*)l,
        16, 0, 0);
}

__device__ __forceinline__ void store_c(float* C, size_t idx, float v) { C[idx] = v; }
__device__ __forceinline__ void store_c(__hip_bfloat16* C, size_t idx, float v) { C[idx] = __float2bfloat16(v); }

// ---------------------------------------------------------------------------
// C[MxN] = alpha * A[MxK] * B^T   (B stored NxK row-major; A,B bf16; fp32 accum)
// m97 structure: 128x128 tile, BK=32, 4 waves, 2 barriers per K-step.
// CSKIP: skip blocks strictly above the diagonal (causal scores).
// KLIM : only accumulate k < bm0+128 (PV GEMM; P is zero beyond the diagonal).
// ---------------------------------------------------------------------------
template<typename CT, bool CSKIP, bool KLIM>
__global__ __launch_bounds__(256)
void gemm_bt(const __hip_bfloat16* __restrict__ A,
             const __hip_bfloat16* __restrict__ B,
             CT* __restrict__ C,
             int M, int N, int K, float alpha)
{
    __shared__ __hip_bfloat16 As[128][32];
    __shared__ __hip_bfloat16 Bs[128][32];

    const int bn0 = blockIdx.x * 128;
    const int bm0 = blockIdx.y * 128;
    if (CSKIP && bn0 >= bm0 + 128) return;   // strictly above diagonal: all masked

    const int tid  = threadIdx.x;
    const int lane = tid & 63;
    const int wave = tid >> 6;

    // staging map: thread t covers LDS bytes [t*16, t*16+16) of each 4KB half
    const int sm = tid >> 2;            // row 0..63 within half
    const int sk = (tid & 3) * 8;       // k element offset

    const __hip_bfloat16* Ag = A + (size_t)(bm0 + sm) * K + sk;
    const __hip_bfloat16* Bg = B + (size_t)(bn0 + sm) * K + sk;

    char* asB = (char*)(&As[0][0]) + wave * 1024;   // wave-uniform LDS base
    char* bsB = (char*)(&Bs[0][0]) + wave * 1024;

    const int wm = (wave >> 1) * 64;    // wave tile origin inside the 128x128 block
    const int wn = (wave & 1) * 64;
    const int fr = lane & 15;           // fragment row (A) / col (B)
    const int fk = (lane >> 4) * 8;     // fragment k offset

    f32x4 acc[4][4] = {};

    const int kend = KLIM ? min(K, bm0 + 128) : K;

    for (int kt = 0; kt < kend; kt += 32) {
        gload_lds16(Ag + kt,                   asB);
        gload_lds16(Ag + kt + (size_t)64 * K,  asB + 4096);
        gload_lds16(Bg + kt,                   bsB);
        gload_lds16(Bg + kt + (size_t)64 * K,  bsB + 4096);
        __syncthreads();   // compiler drains vmcnt before s_barrier

        bf16x8 af[4], bfv[4];
#pragma unroll
        for (int i = 0; i < 4; ++i)
            af[i] = *(const bf16x8*)(&As[wm + i * 16 + fr][fk]);
#pragma unroll
        for (int i = 0; i < 4; ++i)
            bfv[i] = *(const bf16x8*)(&Bs[wn + i * 16 + fr][fk]);

#pragma unroll
        for (int mi = 0; mi < 4; ++mi)
#pragma unroll
            for (int ni = 0; ni < 4; ++ni)
                acc[mi][ni] = __builtin_amdgcn_mfma_f32_16x16x32_bf16(
                    af[mi], bfv[ni], acc[mi][ni], 0, 0, 0);
        __syncthreads();
    }

    // C/D layout: col = lane&15, row = (lane>>4)*4 + reg   [verified m89/m91]
    const int cr = (lane >> 4) * 4;
    const int cc = lane & 15;
#pragma unroll
    for (int mi = 0; mi < 4; ++mi)
#pragma unroll
        for (int ni = 0; ni < 4; ++ni) {
            const int row = bm0 + wm + mi * 16 + cr;
            const int col = bn0 + wn + ni * 16 + cc;
#pragma unroll
            for (int j = 0; j < 4; ++j)
                store_c(C, (size_t)(row + j) * N + col, acc[mi][ni][j] * alpha);
        }
}

// ---------------------------------------------------------------------------
// fp32 -> bf16 conversion, float4 vectorized
// ---------------------------------------------------------------------------
__global__ void f32_to_bf16_vec(const float* __restrict__ in,
                                __hip_bfloat16* __restrict__ out, int n4)
{
    int i = blockIdx.x * 256 + threadIdx.x;
    if (i >= n4) return;
    float4 v = ((const float4*)in)[i];
    union { ushort4 u; __hip_bfloat16 h[4]; } o;
    o.h[0] = __float2bfloat16(v.x);
    o.h[1] = __float2bfloat16(v.y);
    o.h[2] = __float2bfloat16(v.z);
    o.h[3] = __float2bfloat16(v.w);
    ((ushort4*)out)[i] = o.u;
}

// ---------------------------------------------------------------------------
// RoPE cos/sin table: tab[n*64 + j] = (cos, sin)(pos[n] * 10000^(-j/64))
// ---------------------------------------------------------------------------
__global__ void rope_table(const int* __restrict__ pos, float2* __restrict__ tab, int N)
{
    int i = blockIdx.x * 256 + threadIdx.x;
    if (i >= N * 64) return;
    int n = i >> 6, j = i & 63;
    float p = (float)pos[n];
    float ang = p * powf(10000.f, -(float)j * (1.0f / 64.0f));
    tab[i] = make_float2(cosf(ang), sinf(ang));
}

// ---------------------------------------------------------------------------
// Apply interleaved-pair RoPE in place on a (rows x 2048) bf16 tensor.
// pair index pr in [0,1024): head = pr/64, j = pr%64, cols (2*pr, 2*pr+1).
// ---------------------------------------------------------------------------
__global__ void rope_apply(__hip_bfloat16* __restrict__ T,
                           const float2* __restrict__ tab, int total)
{
    int i = blockIdx.x * 256 + threadIdx.x;
    if (i >= total) return;
    int r  = i >> 10;         // row (b*2048 + n)
    int pr = i & 1023;        // pair index
    int n  = r & 2047;        // sequence position
    int j  = pr & 63;
    float2 cs = tab[(n << 6) + j];
    __hip_bfloat162* p = (__hip_bfloat162*)(T + ((size_t)r << 11) + (pr << 1));
    __hip_bfloat162 v = *p;
    float x1 = __bfloat162float(v.x);
    float x2 = __bfloat162float(v.y);
    v.x = __float2bfloat16(cs.x * x1 - cs.y * x2);
    v.y = __float2bfloat16(cs.y * x1 + cs.x * x2);
    *p = v;
}

// ---------------------------------------------------------------------------
// Causal row softmax: P[q][j] = softmax_{j<=q}(S[q][j]) (bf16), 0 for j>q.
// Scale is already folded into S. One 256-thread block per row.
// ---------------------------------------------------------------------------
__global__ void softmax_causal(const float* __restrict__ S,
                               __hip_bfloat16* __restrict__ P, int N)
{
    const int q = blockIdx.x;
    const float* s = S + (size_t)q * N;
    __hip_bfloat16* p = P + (size_t)q * N;
    const int tid = threadIdx.x;

    float m = -1e30f;
    for (int j = tid; j <= q; j += 256) m = fmaxf(m, s[j]);
#pragma unroll
    for (int o = 32; o > 0; o >>= 1) m = fmaxf(m, __shfl_xor(m, o));
    __shared__ float red[4];
    if ((tid & 63) == 0) red[tid >> 6] = m;
    __syncthreads();
    m = fmaxf(fmaxf(red[0], red[1]), fmaxf(red[2], red[3]));

    float sum = 0.f;
    for (int j = tid; j <= q; j += 256) sum += expf(s[j] - m);
#pragma unroll
    for (int o = 32; o > 0; o >>= 1) sum += __shfl_xor(sum, o);
    __shared__ float red2[4];
    if ((tid & 63) == 0) red2[tid >> 6] = sum;
    __syncthreads();
    sum = red2[0] + red2[1] + red2[2] + red2[3];
    const float inv = 1.f / sum;

    for (int j = tid; j < N; j += 256) {
        float v = (j <= q) ? expf(s[j] - m) * inv : 0.f;
        p[j] = __float2bfloat16(v);
    }
}

// ---------------------------------------------------------------------------
// Vt[b][d][k] = V[b][k][d], 32x32 LDS tiles
// ---------------------------------------------------------------------------
__global__ void transpose_bf16(const __hip_bfloat16* __restrict__ V,
                               __hip_bfloat16* __restrict__ Vt, int N)
{
    __shared__ __hip_bfloat16 tile[32][33];
    const size_t bo = (size_t)blockIdx.z * N * N;
    const int k0 = blockIdx.x * 32, d0 = blockIdx.y * 32;
    const int tx = threadIdx.x, ty = threadIdx.y;   // 32 x 8
#pragma unroll
    for (int j = 0; j < 4; ++j)
        tile[ty + 8 * j][tx] = V[bo + (size_t)(k0 + ty + 8 * j) * N + d0 + tx];
    __syncthreads();
#pragma unroll
    for (int j = 0; j < 4; ++j)
        Vt[bo + (size_t)(d0 + ty + 8 * j) * N + k0 + tx] = tile[tx][ty + 8 * j];
}

// ---------------------------------------------------------------------------
extern "C" void kernel_launch(void* const* d_in, const int* in_sizes, int n_in,
                              void* d_out, int out_size, void* d_ws, size_t ws_size,
                              hipStream_t stream)
{
    const float* x  = (const float*)d_in[0];
    const int* pos  = (const int*)d_in[1];
    const float* wq = (const float*)d_in[2];
    const float* wk = (const float*)d_in[3];
    const float* wv = (const float*)d_in[4];
    const float* wo = (const float*)d_in[5];
    float* out = (float*)d_out;

    const int B = 4, N = 2048, D = 2048;
    const int M = B * N;                      // 8192
    const size_t MB = 1ull << 20;
    if (ws_size < 192 * MB) return;           // need 192 MiB scratch

    char* w = (char*)d_ws;
    __hip_bfloat16* Qb  = (__hip_bfloat16*)(w + 0 * MB);
    __hip_bfloat16* Kb  = (__hip_bfloat16*)(w + 32 * MB);
    __hip_bfloat16* Vb  = (__hip_bfloat16*)(w + 64 * MB);
    __hip_bfloat16* wqb = (__hip_bfloat16*)(w + 96 * MB);
    __hip_bfloat16* wkb = (__hip_bfloat16*)(w + 104 * MB);
    __hip_bfloat16* wvb = (__hip_bfloat16*)(w + 112 * MB);
    __hip_bfloat16* wob = (__hip_bfloat16*)(w + 120 * MB);
    __hip_bfloat16* xb  = (__hip_bfloat16*)(w + 128 * MB);  // dead after projections
    __hip_bfloat16* Vt  = xb;                                // alias
    __hip_bfloat16* AO  = (__hip_bfloat16*)(w + 160 * MB);

    // scratch inside d_out (fully overwritten by the final GEMM):
    float*          Sc  = (float*)d_out;                             // 16 MiB
    __hip_bfloat16* Pb  = (__hip_bfloat16*)((char*)d_out + 16 * MB); //  8 MiB
    float2*         tab = (float2*)((char*)d_out + 24 * MB);         //  1 MiB

    // 1. convert inputs/weights to bf16
    f32_to_bf16_vec<<<(M * D / 4 + 255) / 256, 256, 0, stream>>>(x,  xb,  M * D / 4);
    f32_to_bf16_vec<<<(D * D / 4 + 255) / 256, 256, 0, stream>>>(wq, wqb, D * D / 4);
    f32_to_bf16_vec<<<(D * D / 4 + 255) / 256, 256, 0, stream>>>(wk, wkb, D * D / 4);
    f32_to_bf16_vec<<<(D * D / 4 + 255) / 256, 256, 0, stream>>>(wv, wvb, D * D / 4);
    f32_to_bf16_vec<<<(D * D / 4 + 255) / 256, 256, 0, stream>>>(wo, wob, D * D / 4);

    // 2. projections (bf16 out)
    dim3 gp(D / 128, M / 128);
    gemm_bt<__hip_bfloat16, false, false><<<gp, 256, 0, stream>>>(xb, wqb, Qb, M, D, D, 1.f);
    gemm_bt<__hip_bfloat16, false, false><<<gp, 256, 0, stream>>>(xb, wkb, Kb, M, D, D, 1.f);
    gemm_bt<__hip_bfloat16, false, false><<<gp, 256, 0, stream>>>(xb, wvb, Vb, M, D, D, 1.f);

    // 3. RoPE on Q and K
    rope_table<<<(N * 64 + 255) / 256, 256, 0, stream>>>(pos, tab, N);
    rope_apply<<<(M * 1024 + 255) / 256, 256, 0, stream>>>(Qb, tab, M * 1024);
    rope_apply<<<(M * 1024 + 255) / 256, 256, 0, stream>>>(Kb, tab, M * 1024);

    // 4. V transpose (Vt aliases dead xb)
    transpose_bf16<<<dim3(N / 32, N / 32, B), dim3(32, 8), 0, stream>>>(Vb, Vt, N);

    // 5. attention, per batch
    const float scale = 1.0f / sqrtf((float)D);
    for (int b = 0; b < B; ++b) {
        const __hip_bfloat16* Qg  = Qb + (size_t)b * N * D;
        const __hip_bfloat16* Kg  = Kb + (size_t)b * N * D;
        const __hip_bfloat16* Vtg = Vt + (size_t)b * N * D;
        __hip_bfloat16*       AOg = AO + (size_t)b * N * D;
        gemm_bt<float, true, false><<<dim3(16, 16), 256, 0, stream>>>(Qg, Kg, Sc, N, N, D, scale);
        softmax_causal<<<N, 256, 0, stream>>>(Sc, Pb, N);
        gemm_bt<__hip_bfloat16, false, true><<<dim3(16, 16), 256, 0, stream>>>(Pb, Vtg, AOg, N, N, N, 1.f);
    }

    // 6. output projection (fp32 out, overwrites all of d_out)
    gemm_bt<float, false, false><<<dim3(D / 128, M / 128), 256, 0, stream>>>(AO, wob, out, M, D, D, 1.f);
}

// Round 2
// 479.772 us; speedup vs baseline: 1.9034x; 1.9034x over previous
//
#include <hip/hip_runtime.h>
#include <hip/hip_bf16.h>
#include <cstdint>
#include <cmath>

typedef __attribute__((ext_vector_type(4))) float f32x4;
typedef __attribute__((ext_vector_type(8))) short bf16x8;

#define BAR()   __builtin_amdgcn_s_barrier()
#define PRIO1() __builtin_amdgcn_s_setprio(1)
#define PRIO0() __builtin_amdgcn_s_setprio(0)
#define WAITV2() asm volatile("s_waitcnt vmcnt(2)" ::: "memory")
#define WAITV0() asm volatile("s_waitcnt vmcnt(0)" ::: "memory")
#define MM(a,b,c) __builtin_amdgcn_mfma_f32_16x16x32_bf16((a),(b),(c),0,0,0)

__device__ __forceinline__ void gl_lds16(const __hip_bfloat16* g, char* l) {
    __builtin_amdgcn_global_load_lds(
        (const __attribute__((address_space(1))) void*)g,
        (__attribute__((address_space(3))) void*)l, 16, 0, 0);
}
__device__ __forceinline__ void store_c(float* C, size_t i, float v) { C[i] = v; }
__device__ __forceinline__ void store_c(__hip_bfloat16* C, size_t i, float v) { C[i] = __float2bfloat16(v); }

// ---------------------------------------------------------------------------
// 256x256-tile GEMM: C = alpha * A[M x K] * B^T (B stored N x K row-major).
// BK=64, 8 waves (2x4), double-buffered 128KB LDS, st_16x32 XOR swizzle,
// 4 phases per K-tile with counted vmcnt(2), setprio around MFMA clusters.
// LDS layout per 32KB tile: 16x32-elem subtiles (1024B), subtile (sr,sc) at
// (sr*2+sc)*1024, within: r*64 + c*2, swizzled byte ^= ((byte>>9)&1)<<5.
// Staging: linear global_load_lds dest; per-lane pre-swizzled global source.
// CSKIP: skip blocks strictly above causal diagonal. KLIM: k < bm0+256.
// ---------------------------------------------------------------------------
#define LDA_(mi,kk) (*(const bf16x8*)(dA + ((((wr8+(mi))<<1)+(kk))<<10) + rswz))
#define LDB_(ni,kk) (*(const bf16x8*)(dB + ((((wc4+(ni))<<1)+(kk))<<10) + rswz))
#define ST_(s) do{ if((s)<4) gl_lds16(Asrc + (size_t)((s)*64)*lda + ktn, nA + (s)*8192 + wbase); \
                   else      gl_lds16(Bsrc + (size_t)(((s)-4)*64)*ldb + ktn, nB + ((s)-4)*8192 + wbase); }while(0)
#define PH_LOADA(mih) do{ _Pragma("unroll") for(int i_=0;i_<4;++i_){ af[i_][0]=LDA_((mih)*4+i_,0); af[i_][1]=LDA_((mih)*4+i_,1);} }while(0)
#define PH_LOADB(nih) do{ _Pragma("unroll") for(int i_=0;i_<2;++i_){ bfr[i_][0]=LDB_((nih)*2+i_,0); bfr[i_][1]=LDB_((nih)*2+i_,1);} }while(0)
#define PH_MMA(mih,nih) do{ _Pragma("unroll") for(int i_=0;i_<4;++i_){ _Pragma("unroll") for(int j_=0;j_<2;++j_){ \
    f32x4 c_=acc[(mih)*4+i_][(nih)*2+j_]; c_=MM(af[i_][0],bfr[j_][0],c_); c_=MM(af[i_][1],bfr[j_][1],c_); acc[(mih)*4+i_][(nih)*2+j_]=c_; } } }while(0)

#define TILEB(DA,DB,NA,NB) do{ \
    const char* dA=(DA); const char* dB=(DB); char* nA=(NA); char* nB=(NB); \
    if (pf) { ST_(0); ST_(1); WAITV2(); } else { WAITV0(); } \
    BAR(); \
    PH_LOADA(0); PH_LOADB(0); \
    PRIO1(); PH_MMA(0,0); PRIO0(); BAR(); \
    if (pf) { ST_(2); ST_(3); } \
    PH_LOADB(1); \
    BAR(); PRIO1(); PH_MMA(0,1); PRIO0(); BAR(); \
    if (pf) { ST_(4); ST_(5); } \
    PH_LOADA(1); \
    BAR(); PRIO1(); PH_MMA(1,1); PRIO0(); BAR(); \
    if (pf) { ST_(6); ST_(7); } \
    PH_LOADB(0); \
    BAR(); PRIO1(); PH_MMA(1,0); PRIO0(); BAR(); \
}while(0)

template<typename CT, bool CSKIP, bool KLIM>
__global__ __launch_bounds__(512, 2)
void gemm256(const __hip_bfloat16* __restrict__ A, const __hip_bfloat16* __restrict__ B,
             CT* __restrict__ C, int K, int lda, int ldb, int ldc, int nbx,
             float alpha, size_t sA, size_t sB, size_t sC)
{
    __shared__ char lds[131072];
    char* const lA0 = lds;
    char* const lB0 = lds + 32768;
    char* const lA1 = lds + 65536;
    char* const lB1 = lds + 98304;

    // bijective XCD-aware swizzle (m204)
    const int nwg = gridDim.x;
    const int q8 = nwg >> 3, r8 = nwg & 7;
    const int xcd = blockIdx.x & 7, blk = blockIdx.x >> 3;
    const int wg = (xcd < r8 ? xcd * (q8 + 1) : r8 * (q8 + 1) + (xcd - r8) * q8) + blk;
    const int bx = wg % nbx, by = wg / nbx;
    const int bm0 = by * 256, bn0 = bx * 256;
    if (CSKIP && bn0 >= bm0 + 256) return;

    A += sA * blockIdx.y; B += sB * blockIdx.y; C += sC * blockIdx.y;

    const int tid  = threadIdx.x;
    const int lane = tid & 63;
    const int w    = tid >> 6;
    const int wr8  = (w >> 2) * 8;
    const int wc4  = (w & 3) * 4;
    const int wbase = w * 1024;

    // staging: invert LDS chunk position -> (row, col) in tile (pre-swizzled source)
    const int pq  = lane * 16;
    const int uq  = pq ^ (((pq >> 9) & 1) << 5);
    const int sr0 = (w >> 1) * 16 + (uq >> 6);
    const int sc0 = (w & 1) * 32 + ((uq & 63) >> 1);
    const __hip_bfloat16* Asrc = A + (size_t)(bm0 + sr0) * lda + sc0;
    const __hip_bfloat16* Bsrc = B + (size_t)(bn0 + sr0) * ldb + sc0;

    // ds_read per-lane swizzled base within a subtile-pair
    const int rb   = (lane & 15) * 64 + (lane >> 4) * 16;
    const int rswz = rb ^ (((rb >> 9) & 1) << 5);

    f32x4 acc[8][4] = {};
    bf16x8 af[4][2], bfr[2][2];

    const int klim = bm0 + 256;
    const int kend = KLIM ? (K < klim ? K : klim) : K;
    const int nt   = kend >> 6;          // always even for our shapes

    {   // prologue: stage tile 0 into buf0 (8 x 8KB), no wait yet
        char* nA = lA0; char* nB = lB0; const int ktn = 0;
        ST_(0); ST_(1); ST_(2); ST_(3); ST_(4); ST_(5); ST_(6); ST_(7);
    }
    for (int t = 0; t < nt; t += 2) {
        {   const bool pf = (t + 1 < nt); const int ktn = (t + 1) << 6;
            TILEB(lA0, lB0, lA1, lB1);
        }
        {   const bool pf = (t + 2 < nt); const int ktn = (t + 2) << 6;
            TILEB(lA1, lB1, lA0, lB0);
        }
    }

    // epilogue: C/D layout col=lane&15, row=(lane>>4)*4+j
    const int cr = (lane >> 4) * 4, cc = lane & 15;
    const int wrow = bm0 + (w >> 2) * 128, wcol = bn0 + (w & 3) * 64;
#pragma unroll
    for (int mi = 0; mi < 8; ++mi)
#pragma unroll
        for (int ni = 0; ni < 4; ++ni) {
            const int row = wrow + mi * 16 + cr;
            const int col = wcol + ni * 16 + cc;
#pragma unroll
            for (int j = 0; j < 4; ++j)
                store_c(C, (size_t)(row + j) * ldc + col, acc[mi][ni][j] * alpha);
        }
}

// ---------------------------------------------------------------------------
__global__ void f32_to_bf16_vec(const float* __restrict__ in,
                                __hip_bfloat16* __restrict__ out, int n4)
{
    int i = blockIdx.x * 256 + threadIdx.x;
    if (i >= n4) return;
    float4 v = ((const float4*)in)[i];
    union { ushort4 u; __hip_bfloat16 h[4]; } o;
    o.h[0] = __float2bfloat16(v.x);
    o.h[1] = __float2bfloat16(v.y);
    o.h[2] = __float2bfloat16(v.z);
    o.h[3] = __float2bfloat16(v.w);
    ((ushort4*)out)[i] = o.u;
}

__global__ void rope_table(const int* __restrict__ pos, float2* __restrict__ tab, int N)
{
    int i = blockIdx.x * 256 + threadIdx.x;
    if (i >= N * 64) return;
    int n = i >> 6, j = i & 63;
    float p = (float)pos[n];
    float ang = p * powf(10000.f, -(float)j * (1.0f / 64.0f));
    tab[i] = make_float2(cosf(ang), sinf(ang));
}

__global__ void rope_apply(__hip_bfloat16* __restrict__ T,
                           const float2* __restrict__ tab, int total)
{
    int i = blockIdx.x * 256 + threadIdx.x;
    if (i >= total) return;
    int r  = i >> 10;         // row (b*2048 + n)
    int pr = i & 1023;        // pair index
    int n  = r & 2047;
    int j  = pr & 63;
    float2 cs = tab[(n << 6) + j];
    __hip_bfloat162* p = (__hip_bfloat162*)(T + ((size_t)r << 11) + (pr << 1));
    __hip_bfloat162 v = *p;
    float x1 = __bfloat162float(v.x);
    float x2 = __bfloat162float(v.y);
    v.x = __float2bfloat16(cs.x * x1 - cs.y * x2);
    v.y = __float2bfloat16(cs.y * x1 + cs.x * x2);
    *p = v;
}

// ---------------------------------------------------------------------------
// In-place causal softmax: reads fp32 row q of S, writes bf16 P over the
// same row (row stride stays 8KB = 4096 bf16 elements). Row staged in LDS.
// ---------------------------------------------------------------------------
__global__ void softmax_causal_ip(float* __restrict__ S, int N)
{
    const int q = blockIdx.x;
    float* srow = S + ((size_t)blockIdx.y * N + q) * N;
    __shared__ float buf[2048];
    __shared__ float red[8];
    const int tid = threadIdx.x;

    float4* b4 = (float4*)buf;
    const float4* s4 = (const float4*)srow;
    for (int i = tid; i < N / 4; i += 256) b4[i] = s4[i];
    __syncthreads();

    float m = -1e30f;
    for (int j = tid; j <= q; j += 256) m = fmaxf(m, buf[j]);
#pragma unroll
    for (int o = 32; o > 0; o >>= 1) m = fmaxf(m, __shfl_xor(m, o));
    if ((tid & 63) == 0) red[tid >> 6] = m;
    __syncthreads();
    m = fmaxf(fmaxf(red[0], red[1]), fmaxf(red[2], red[3]));

    float sum = 0.f;
    for (int j = tid; j <= q; j += 256) { float e = __expf(buf[j] - m); buf[j] = e; sum += e; }
#pragma unroll
    for (int o = 32; o > 0; o >>= 1) sum += __shfl_xor(sum, o);
    if ((tid & 63) == 0) red[4 + (tid >> 6)] = sum;
    __syncthreads();
    const float inv = 1.f / (red[4] + red[5] + red[6] + red[7]);

    __hip_bfloat162* p2 = (__hip_bfloat162*)srow;
    for (int i = tid; i < N / 2; i += 256) {
        int j0 = i * 2;
        __hip_bfloat162 h;
        h.x = __float2bfloat16(j0     <= q ? buf[j0]     * inv : 0.f);
        h.y = __float2bfloat16(j0 + 1 <= q ? buf[j0 + 1] * inv : 0.f);
        p2[i] = h;
    }
}

__global__ void transpose_bf16(const __hip_bfloat16* __restrict__ V,
                               __hip_bfloat16* __restrict__ Vt, int N)
{
    __shared__ __hip_bfloat16 tile[32][33];
    const size_t bo = (size_t)blockIdx.z * N * N;
    const int k0 = blockIdx.x * 32, d0 = blockIdx.y * 32;
    const int tx = threadIdx.x, ty = threadIdx.y;   // 32 x 8
#pragma unroll
    for (int j = 0; j < 4; ++j)
        tile[ty + 8 * j][tx] = V[bo + (size_t)(k0 + ty + 8 * j) * N + d0 + tx];
    __syncthreads();
#pragma unroll
    for (int j = 0; j < 4; ++j)
        Vt[bo + (size_t)(d0 + ty + 8 * j) * N + k0 + tx] = tile[tx][ty + 8 * j];
}

// ---------------------------------------------------------------------------
extern "C" void kernel_launch(void* const* d_in, const int* in_sizes, int n_in,
                              void* d_out, int out_size, void* d_ws, size_t ws_size,
                              hipStream_t stream)
{
    const float* x  = (const float*)d_in[0];
    const int* pos  = (const int*)d_in[1];
    const float* wq = (const float*)d_in[2];
    const float* wk = (const float*)d_in[3];
    const float* wv = (const float*)d_in[4];
    const float* wo = (const float*)d_in[5];
    float* out = (float*)d_out;

    const int B = 4, N = 2048, D = 2048;
    const int M = B * N;                      // 8192
    const size_t MB = 1ull << 20;
    if (ws_size < 192 * MB) return;

    char* w = (char*)d_ws;
    __hip_bfloat16* Qb  = (__hip_bfloat16*)(w + 0 * MB);
    __hip_bfloat16* Kb  = (__hip_bfloat16*)(w + 32 * MB);
    __hip_bfloat16* Vb  = (__hip_bfloat16*)(w + 64 * MB);
    __hip_bfloat16* wqb = (__hip_bfloat16*)(w + 96 * MB);
    __hip_bfloat16* wkb = (__hip_bfloat16*)(w + 104 * MB);
    __hip_bfloat16* wvb = (__hip_bfloat16*)(w + 112 * MB);
    __hip_bfloat16* wob = (__hip_bfloat16*)(w + 120 * MB);
    __hip_bfloat16* xb  = (__hip_bfloat16*)(w + 128 * MB);  // dead after projections
    __hip_bfloat16* Vt  = xb;                                // alias
    __hip_bfloat16* AO  = (__hip_bfloat16*)(w + 160 * MB);

    float2* tab = (float2*)wqb;          // wqb dead after Q projection
    float*  Sal = (float*)d_out;         // S for all 4 batches = 64MB = d_out

    // 1. convert to bf16
    f32_to_bf16_vec<<<(M * D / 4 + 255) / 256, 256, 0, stream>>>(x,  xb,  M * D / 4);
    f32_to_bf16_vec<<<(D * D / 4 + 255) / 256, 256, 0, stream>>>(wq, wqb, D * D / 4);
    f32_to_bf16_vec<<<(D * D / 4 + 255) / 256, 256, 0, stream>>>(wk, wkb, D * D / 4);
    f32_to_bf16_vec<<<(D * D / 4 + 255) / 256, 256, 0, stream>>>(wv, wvb, D * D / 4);
    f32_to_bf16_vec<<<(D * D / 4 + 255) / 256, 256, 0, stream>>>(wo, wob, D * D / 4);

    // 2. projections: grid 8x32 = 256 wgs
    const int nbxP = D / 256;
    dim3 gp((D / 256) * (M / 256), 1);
    gemm256<__hip_bfloat16, false, false><<<gp, 512, 0, stream>>>(xb, wqb, Qb, D, D, D, D, nbxP, 1.f, 0, 0, 0);
    gemm256<__hip_bfloat16, false, false><<<gp, 512, 0, stream>>>(xb, wkb, Kb, D, D, D, D, nbxP, 1.f, 0, 0, 0);
    gemm256<__hip_bfloat16, false, false><<<gp, 512, 0, stream>>>(xb, wvb, Vb, D, D, D, D, nbxP, 1.f, 0, 0, 0);

    // 3. RoPE
    rope_table<<<(N * 64 + 255) / 256, 256, 0, stream>>>(pos, tab, N);
    rope_apply<<<(M * 1024 + 255) / 256, 256, 0, stream>>>(Qb, tab, M * 1024);
    rope_apply<<<(M * 1024 + 255) / 256, 256, 0, stream>>>(Kb, tab, M * 1024);

    // 4. V transpose (batched)
    transpose_bf16<<<dim3(N / 32, N / 32, B), dim3(32, 8), 0, stream>>>(Vb, Vt, N);

    // 5. attention, all batches in one dispatch each
    const float scale = 1.0f / sqrtf((float)D);
    const int nbxA = N / 256;
    dim3 ga(nbxA * (N / 256), B);
    gemm256<float, true, false><<<ga, 512, 0, stream>>>(
        Qb, Kb, Sal, D, D, D, N, nbxA, scale, (size_t)N * D, (size_t)N * D, (size_t)N * N);
    softmax_causal_ip<<<dim3(N, B), 256, 0, stream>>>(Sal, N);
    gemm256<__hip_bfloat16, false, true><<<ga, 512, 0, stream>>>(
        (const __hip_bfloat16*)Sal, Vt, AO, N, 2 * N, D, D, nbxA, 1.f,
        (size_t)2 * N * N, (size_t)N * D, (size_t)N * D);

    // 6. output projection (fp32, overwrites all of d_out)
    gemm256<float, false, false><<<gp, 512, 0, stream>>>(AO, wob, out, D, D, D, D, nbxP, 1.f, 0, 0, 0);
}